// Round 13
// baseline (503.104 us; speedup 1.0000x reference)
//
#include <hip/hip_runtime.h>
#include <math.h>

#define N_NODES 50000
#define N_EDGES 800000
#define DIM 128
#define PAD 128             // bucket capacity; Poisson(16), P(deg>=128) ~ 0
#define NPART 8             // dst partitions, aligned to XCDs via blockIdx%8
#define PART_SZ 6250        // 50000/8
#define SCAT_CHUNKS 3125    // 3125*256 = 800000
#define SCAT_BLOCKS (SCAT_CHUNKS * NPART)   // 25000
#define GEMM_BLOCKS 782     // 782*4 waves*16 rows >= 50000

typedef __attribute__((ext_vector_type(8))) short short8;
typedef __attribute__((ext_vector_type(4))) float floatx4;

// f32 -> bf16 bits, round-to-nearest-even (matches v_cvt / numpy)
__device__ __forceinline__ unsigned short f32_to_bf16(float f) {
    unsigned int u = __float_as_uint(f);
    u += 0x7fffu + ((u >> 16) & 1u);
    return (unsigned short)(u >> 16);
}
__device__ __forceinline__ float bf16_to_f32(unsigned short h) {
    return __uint_as_float((unsigned int)h << 16);
}

// ---------------- MFMA GEMM body: out = relu(A @ (cg*W + cm*I) + bias) ------
// W' folded during LDS staging (R9 known-good form).

template <bool AF32>
__device__ __forceinline__ void gemm_body(int bid, const void* __restrict__ Av,
                                          const float* __restrict__ W,
                                          const float* __restrict__ bias,
                                          float* __restrict__ outF,
                                          unsigned short* __restrict__ outB,
                                          float cm, float cg,
                                          unsigned short (*WT)[136]) {
    for (int idx = threadIdx.x; idx < 128 * 128; idx += 256) {
        int k = idx >> 7, n = idx & 127;
        float wv = cg * W[idx] + ((n == k) ? cm : 0.f);
        WT[n][k] = f32_to_bf16(wv);
    }
    __syncthreads();

    int wave = threadIdx.x >> 6;
    int lane = threadIdx.x & 63;
    int r0 = (bid * 4 + wave) * 16;
    if (r0 >= N_NODES) return;                 // 16 | 50000, full tiles only

    int mrow = lane & 15;                      // A row within tile; also C col
    int quad = lane >> 4;

    floatx4 acc[8];
#pragma unroll
    for (int t = 0; t < 8; t++) acc[t] = {0.f, 0.f, 0.f, 0.f};

#pragma unroll
    for (int k0 = 0; k0 < 128; k0 += 32) {
        short8 a;
        if constexpr (AF32) {
            const float* arow = (const float*)Av + (size_t)(r0 + mrow) * DIM;
            floatx4 alo = *(const floatx4*)(const void*)(arow + k0 + quad * 8);
            floatx4 ahi = *(const floatx4*)(const void*)(arow + k0 + quad * 8 + 4);
#pragma unroll
            for (int j = 0; j < 4; j++) a[j] = (short)f32_to_bf16(alo[j]);
#pragma unroll
            for (int j = 0; j < 4; j++) a[4 + j] = (short)f32_to_bf16(ahi[j]);
        } else {
            const unsigned short* arow = (const unsigned short*)Av + (size_t)(r0 + mrow) * DIM;
            a = *(const short8*)(const void*)(arow + k0 + quad * 8);
        }
#pragma unroll
        for (int t = 0; t < 8; t++) {
            short8 b = *(const short8*)(const void*)(&WT[t * 16 + mrow][k0 + quad * 8]);
            acc[t] = __builtin_amdgcn_mfma_f32_16x16x32_bf16(a, b, acc[t], 0, 0, 0);
        }
    }

    // C/D layout: col = lane&15, row = quad*4 + i  [verified m89/m91]
#pragma unroll
    for (int t = 0; t < 8; t++) {
        int col = t * 16 + mrow;
        float bv = bias ? bias[col] : 0.f;
#pragma unroll
        for (int i = 0; i < 4; i++) {
            int row = r0 + quad * 4 + i;
            size_t off = (size_t)row * DIM + col;
            float v = fmaxf(acc[t][i] + bv, 0.f);
            if (outF) outF[off] = v;
            if (outB) outB[off] = f32_to_bf16(v);
        }
    }
}

// ---------------- fused: XCD-partitioned bucket scatter + x0 gemm -----------
// Scatter blocks: block b (b < SCAT_BLOCKS) handles edge chunk b>>3, keeps
// only dst in partition b&7 (= XCD b%8 by round-robin dispatch). All cnt &
// bucket lines of a partition are dirtied by ONE XCD's L2 -> writeback once
// (R12's scatter_pad: 51MB WRITE for 6.4MB payload = 8-XCD amplification).
// Cost: dst read 8x (streaming, L3-hot). gemm0 rides in blocks [SCAT_BLOCKS..).

__global__ __launch_bounds__(256) void scatter_gemm0(const int* __restrict__ src,
                                                     const int* __restrict__ dst,
                                                     const float* __restrict__ ew,
                                                     int* __restrict__ cnt,
                                                     int2* __restrict__ bucket,
                                                     const float* __restrict__ x,
                                                     const float* __restrict__ Wlin,
                                                     const float* __restrict__ blin,
                                                     unsigned short* __restrict__ x0B) {
    __shared__ unsigned short WT[128][136];
    if (blockIdx.x < SCAT_BLOCKS) {
        int part = blockIdx.x & (NPART - 1);
        int e = (blockIdx.x >> 3) * 256 + threadIdx.x;
        int lo = part * PART_SZ;
        if (e < N_EDGES) {
            int d = dst[e];
            if ((unsigned)(d - lo) < PART_SZ) {
                int pos = atomicAdd(&cnt[d], 1);
                if (pos < PAD) {               // structurally unreachable guard
                    int2 p; p.x = src[e]; p.y = __float_as_int(ew[e]);
                    bucket[(size_t)d * PAD + pos] = p;
                }
            }
        }
    } else {
        gemm_body<true>(blockIdx.x - SCAT_BLOCKS, x, Wlin, blin,
                        nullptr, x0B, 0.f, 1.f, WT);
    }
}

// ---------------- fused SpMM + residual mix (wave-per-node, ILP-4) ----------
// One 64-lane wave per node: lane = (edge-group eg 0..3, feature-octet 0..15).
// Loop steps 16 edges: 4 independent (ep, row-gather) pairs in flight/lane.
// ~46us/dispatch = random-line service floor (R5/R8/R9/R10 evidence).

__global__ __launch_bounds__(256) void spmm8(const unsigned short* __restrict__ hB,
                                             const unsigned short* __restrict__ x0B,
                                             const int* __restrict__ cnt,
                                             const int2* __restrict__ bucket,
                                             unsigned short* __restrict__ mB) {
    int node = blockIdx.x * 4 + (threadIdx.x >> 6);   // 4 waves/block
    int lane = threadIdx.x & 63;
    int eg = lane >> 4;                               // edge group 0..3
    int fb = (lane & 15) * 8;                         // feature octet
    int end = min(cnt[node], PAD);
    const int2* ep = bucket + (size_t)node * PAD;
    float acc[8] = {0.f, 0.f, 0.f, 0.f, 0.f, 0.f, 0.f, 0.f};
    if (end > 0) {
        int last = end - 1;
        for (int i = 0; i < end; i += 16) {
            int i0 = i + eg, i1 = i0 + 4, i2 = i0 + 8, i3 = i0 + 12;
            int2 e0 = ep[min(i0, last)];
            int2 e1 = ep[min(i1, last)];
            int2 e2 = ep[min(i2, last)];
            int2 e3 = ep[min(i3, last)];
            short8 r0 = *(const short8*)(const void*)(hB + (size_t)e0.x * DIM + fb);
            short8 r1 = *(const short8*)(const void*)(hB + (size_t)e1.x * DIM + fb);
            short8 r2 = *(const short8*)(const void*)(hB + (size_t)e2.x * DIM + fb);
            short8 r3 = *(const short8*)(const void*)(hB + (size_t)e3.x * DIM + fb);
            float w0 = (i0 < end) ? __int_as_float(e0.y) : 0.f;
            float w1 = (i1 < end) ? __int_as_float(e1.y) : 0.f;
            float w2 = (i2 < end) ? __int_as_float(e2.y) : 0.f;
            float w3 = (i3 < end) ? __int_as_float(e3.y) : 0.f;
#pragma unroll
            for (int j = 0; j < 8; j++) {
                acc[j] = fmaf(w0, bf16_to_f32((unsigned short)r0[j]), acc[j]);
                acc[j] = fmaf(w1, bf16_to_f32((unsigned short)r1[j]), acc[j]);
                acc[j] = fmaf(w2, bf16_to_f32((unsigned short)r2[j]), acc[j]);
                acc[j] = fmaf(w3, bf16_to_f32((unsigned short)r3[j]), acc[j]);
            }
        }
    }
    // reduce the 4 edge groups into lanes 0..15
#pragma unroll
    for (int j = 0; j < 8; j++) {
        acc[j] += __shfl_down(acc[j], 32);
        acc[j] += __shfl_down(acc[j], 16);
    }
    if (lane < 16) {
        size_t off = (size_t)node * DIM + fb;
        short8 xv = *(const short8*)(const void*)(x0B + off);
        short8 o;
#pragma unroll
        for (int j = 0; j < 8; j++)
            o[j] = (short)f32_to_bf16(0.9f * acc[j]
                                      + 0.1f * bf16_to_f32((unsigned short)xv[j]));
        *(short8*)(void*)(mB + off) = o;
    }
}

// ---------------- layer GEMM wrapper ----------------

__global__ __launch_bounds__(256) void gemm_layer(const unsigned short* __restrict__ A,
                                                  const float* __restrict__ W,
                                                  float* __restrict__ outF,
                                                  unsigned short* __restrict__ outB,
                                                  float cm, float cg) {
    __shared__ unsigned short WT[128][136];
    gemm_body<false>(blockIdx.x, A, W, nullptr, outF, outB, cm, cg, WT);
}

// ---------------- launch ----------------

extern "C" void kernel_launch(void* const* d_in, const int* in_sizes, int n_in,
                              void* d_out, int out_size, void* d_ws, size_t ws_size,
                              hipStream_t stream) {
    const float* x    = (const float*)d_in[0];
    const float* ew   = (const float*)d_in[1];
    const float* Wlin = (const float*)d_in[2];
    const float* blin = (const float*)d_in[3];
    const float* Wcv  = (const float*)d_in[4];
    const int* eidx = (const int*)d_in[5];
    const int* esrc = eidx;
    const int* edst = eidx + N_EDGES;
    float* out = (float*)d_out;

    char* ws = (char*)d_ws;
    unsigned short* x0B = (unsigned short*)(ws);             // 12.8 MB bf16 x0 rows
    unsigned short* mB  = (unsigned short*)(ws + 12800000);  // 12.8 MB bf16 m rows
    unsigned short* hB  = (unsigned short*)(ws + 25600000);  // 12.8 MB bf16 h rows
    int* cnt            = (int*)(ws + 38400000);             // N*4 (degree/cursor)
    int2* bucket        = (int2*)(ws + 38600064);            // N*PAD*8 = 51.2 MB
    // total ~89.8 MB

    // bucket build (XCD-partitioned) + x0 gemm in one launch
    (void)hipMemsetAsync(cnt, 0, N_NODES * sizeof(int), stream);
    scatter_gemm0<<<SCAT_BLOCKS + GEMM_BLOCKS, 256, 0, stream>>>(
        esrc, edst, ew, cnt, bucket, x, Wlin, blin, x0B);

    const unsigned short* hin = x0B;
    for (int l = 0; l < 8; l++) {
        spmm8<<<N_NODES / 4, 256, 0, stream>>>(hin, x0B, cnt, bucket, mB);
        float beta = logf(0.5f / (float)(l + 1) + 1.f);
        gemm_layer<<<GEMM_BLOCKS, 256, 0, stream>>>(mB, Wcv + (size_t)l * DIM * DIM,
                                                    (l == 7) ? out : nullptr,
                                                    (l < 7) ? hB : nullptr,
                                                    1.f - beta, beta);
        hin = hB;
    }
}